// Round 13
// baseline (69.339 us; speedup 1.0000x reference)
//
#include <hip/hip_runtime.h>

// Trilinear warp (SpatialTransformer): vol [B=2,D=160,H=192,W=160,C=2] f32,
// flow [B,D,H,W,3] f32 ('ij'). Output f32, same shape as vol.
//
// R12 (65.8us): DMA staging (global_load_lds), linear LDS, conflicts halved.
// Now VALU/issue-limited (~64% VALU-busy at bench speed). R13 cuts instrs:
//  - no LDS-coord clamps (HW OOB ds_read -> 0; fixup overwrites those lanes)
//  - flow-based ok-test: f in [-4,4) on all 6 comps => in staged region
//    (min3/max3 + 2 cmps vs 6 index cmps); conservative at edges -> fixup
//  - packed f32: v_pk_mul/v_pk_fma via ext_vector float2 (bit-identical)
//  - interior blocks (60%): clamp-free staging loop (uniform branch)

constexpr int Bb = 2, Dd = 160, Hh = 192, Ww = 160;
constexpr int HW  = Hh * Ww;          // 30720
constexpr int VOX = Dd * HW;          // 4,915,200 voxels per batch

constexpr int TD = 8,  TH = 16, TW = 16;   // output tile (2048 voxels)
constexpr int RD = TD + 8;                 // 16  staged region (halo 4)
constexpr int RH = TH + 8;                 // 24
constexpr int RW = TW + 8;                 // 24  (extent always even)
constexpr int RWP = 24;                    // UNPADDED row stride (float2) — linear for DMA
constexpr int QROW = RW / 2;               // 12 float4 quads per row
constexpr int NQ = RD * RH * QROW;         // 4608 staged quads (i*16B linear)
constexpr int ND = Dd / TD, NH = Hh / TH, NW = Ww / TW;   // 20, 12, 10
constexpr int NBLK = Bb * ND * NH * NW;                   // 4800
constexpr int BLOCK = 1024;                // 16 waves; 2 voxels per thread
constexpr size_t LDS_BYTES = (size_t)NQ * 16;             // 73728 B

typedef float v2f __attribute__((ext_vector_type(2)));
__device__ __forceinline__ v2f splat2(float s) { return (v2f){s, s}; }

// Exact reference math + global gathers — rare out-of-region lanes only.
// Identical formulas/op-order to the reference.
__device__ __forceinline__ void sample_global(const float2* __restrict__ v2,
                                              int d, int h, int w,
                                              float fx, float fy, float fz,
                                              float& oxv, float& oyv)
{
    const float mx = (float)(Dd - 1), my = (float)(Hh - 1), mz = (float)(Ww - 1);
    const float lxf = (float)d + fx;
    const float lyf = (float)h + fy;
    const float lzf = (float)w + fz;

    const float l0x = fminf(fmaxf(floorf(lxf), 0.0f), mx);
    const float l0y = fminf(fmaxf(floorf(lyf), 0.0f), my);
    const float l0z = fminf(fmaxf(floorf(lzf), 0.0f), mz);
    const float l1x = fminf(l0x + 1.0f, mx);
    const float l1y = fminf(l0y + 1.0f, my);
    const float l1z = fminf(l0z + 1.0f, mz);

    const float d1x = l1x - lxf, d0x = 1.0f - d1x;
    const float d1y = l1y - lyf, d0y = 1.0f - d1y;
    const float d1z = l1z - lzf, d0z = 1.0f - d1z;

    const int i0x = (int)l0x, i1x = (int)l1x;
    const int i0y = (int)l0y, i1y = (int)l1y;
    const int i0z = (int)l0z, i1z = (int)l1z;

    const int rx0 = i0x * HW, rx1 = i1x * HW;
    const int ry0 = i0y * Ww, ry1 = i1y * Ww;
    const float2 c000 = v2[rx0 + ry0 + i0z], c001 = v2[rx0 + ry0 + i1z];
    const float2 c010 = v2[rx0 + ry1 + i0z], c011 = v2[rx0 + ry1 + i1z];
    const float2 c100 = v2[rx1 + ry0 + i0z], c101 = v2[rx1 + ry0 + i1z];
    const float2 c110 = v2[rx1 + ry1 + i0z], c111 = v2[rx1 + ry1 + i1z];

    const float w000 = d1x * d1y * d1z, w001 = d1x * d1y * d0z;
    const float w010 = d1x * d0y * d1z, w011 = d1x * d0y * d0z;
    const float w100 = d0x * d1y * d1z, w101 = d0x * d1y * d0z;
    const float w110 = d0x * d0y * d1z, w111 = d0x * d0y * d0z;

    oxv = w000 * c000.x;
    oyv = w000 * c000.y;
    oxv = fmaf(w001, c001.x, oxv);  oyv = fmaf(w001, c001.y, oyv);
    oxv = fmaf(w010, c010.x, oxv);  oyv = fmaf(w010, c010.y, oyv);
    oxv = fmaf(w011, c011.x, oxv);  oyv = fmaf(w011, c011.y, oyv);
    oxv = fmaf(w100, c100.x, oxv);  oyv = fmaf(w100, c100.y, oyv);
    oxv = fmaf(w101, c101.x, oxv);  oyv = fmaf(w101, c101.y, oyv);
    oxv = fmaf(w110, c110.x, oxv);  oyv = fmaf(w110, c110.y, oyv);
    oxv = fmaf(w111, c111.x, oxv);  oyv = fmaf(w111, c111.y, oyv);
}

__global__ __launch_bounds__(BLOCK, 8)   // 8 waves/EU => VGPR<=64 => 2 blocks/CU
void SpatialTransformer_44418551776013_kernel(const float* __restrict__ vol,
                                              const float* __restrict__ flow,
                                              float* __restrict__ out)
{
    extern __shared__ float2 sv[];   // [RD][RH][RWP], linear
    const v2f* __restrict__ svv = reinterpret_cast<const v2f*>(sv);
    const int tid = threadIdx.x;

    // bijective XCD swizzle (NBLK % 8 == 0). Validated: FETCH 222 -> 132 MB.
    constexpr int CPX = NBLK / 8;    // 600
    int bid = (int)(blockIdx.x % 8) * CPX + (int)(blockIdx.x / 8);

    const int bw = bid % NW;  bid /= NW;
    const int bh = bid % NH;  bid /= NH;
    const int bd = bid % ND;
    const int b  = bid / ND;
    const int d0 = bd * TD, h0 = bh * TH, w0 = bw * TW;

    // staged region = clip(tile +- 4); block-uniform -> SGPRs
    const int ox = max(0, d0 - 4), oy = max(0, h0 - 4), oz = max(0, w0 - 4);
    const int ex = min(Dd - 1, d0 + TD + 3) - ox + 1;   // <= RD
    const int ey = min(Hh - 1, h0 + TH + 3) - oy + 1;   // <= RH
    const int ez = min(Ww - 1, w0 + TW + 3) - oz + 1;   // <= RW, even
    const int qz = ez >> 1;

    // compute mapping: (td, th, tw2); thread owns voxels (d,h,w) & (d,h,w+1)
    const int tw2 = tid & 7;             // w-pair index 0..7
    const int th  = (tid >> 3) & 15;     // 0..15
    const int td  = tid >> 7;            // 0..7
    const int h = h0 + th;
    const int w = w0 + 2 * tw2;
    const int d = d0 + td;
    const int gidx = ((b * Dd + d) * Hh + h) * Ww + w;   // even

    // flow for BOTH voxels = 6 contiguous floats: float4 + float2
    const float4 fA = *reinterpret_cast<const float4*>(flow + (size_t)gidx * 3);
    const float2 fB = *reinterpret_cast<const float2*>(flow + (size_t)gidx * 3 + 4);
    // voxel 1: (fA.x, fA.y, fA.z)   voxel 2: (fA.w, fB.x, fB.y)

    const float2* __restrict__ v2 =
        reinterpret_cast<const float2*>(vol) + (size_t)b * VOX;

    // ---- stage region via global_load_lds DMA (16B/lane, linear dest) ----
    // Interior blocks (60%): extents are full -> clamp-free body (uniform
    // SGPR branch). Edge blocks: clamped source (dup lines -> L2 hits).
    if ((ex == RD) & (ey == RH) & (ez == RW)) {
        #pragma unroll 1
        for (int k = 0; k < 5; ++k) {
            const int i = tid + k * BLOCK;
            if (i < NQ) {                        // wave-uniform tail (512-aligned)
                const int lq = i % QROW;         // compile-time divisors
                const int t  = i / QROW;
                const int ly = t % RH;
                const int lx = t / RH;
                const float2* src =
                    v2 + ((size_t)(ox + lx) * HW + (oy + ly) * Ww + oz + 2 * lq);
                __builtin_amdgcn_global_load_lds(
                    (const __attribute__((address_space(1))) void*)src,
                    (__attribute__((address_space(3))) void*)(sv + (size_t)2 * i),
                    16, 0, 0);
            }
        }
    } else {
        #pragma unroll 1
        for (int k = 0; k < 5; ++k) {
            const int i = tid + k * BLOCK;
            if (i < NQ) {
                int lq = i % QROW;
                const int t  = i / QROW;
                int ly = t % RH;
                int lx = t / RH;
                lx = min(lx, ex - 1);  ly = min(ly, ey - 1);  lq = min(lq, qz - 1);
                const float2* src =
                    v2 + ((size_t)(ox + lx) * HW + (oy + ly) * Ww + oz + 2 * lq);
                __builtin_amdgcn_global_load_lds(
                    (const __attribute__((address_space(1))) void*)src,
                    (__attribute__((address_space(3))) void*)(sv + (size_t)2 * i),
                    16, 0, 0);
            }
        }
    }
    __syncthreads();   // drains vmcnt(0) before s_barrier

    // Branchless LDS sample. ok = flow in [-4,4)^3 => all clamped corner
    // indices provably inside the staged clipped region. not-ok lanes may
    // read OOB LDS (HW returns 0, never faults) — fixup overwrites them.
    auto sample_lds = [&](int dd, int ww, float fx, float fy, float fz,
                          v2f& o, bool& ok) {
        const float mn3 = fminf(fminf(fx, fy), fz);   // v_min3_f32
        const float mx3 = fmaxf(fmaxf(fx, fy), fz);   // v_max3_f32
        ok = (mn3 >= -4.0f) & (mx3 < 4.0f);

        const float lxf = (float)dd + fx;
        const float lyf = (float)h  + fy;
        const float lzf = (float)ww + fz;

        // integer floor path (R10-validated bit-identical)
        const int i0x = min(max(__float2int_rd(lxf), 0), Dd - 1);  // v_med3
        const int i0y = min(max(__float2int_rd(lyf), 0), Hh - 1);
        const int i0z = min(max(__float2int_rd(lzf), 0), Ww - 1);
        const int i1x = min(i0x + 1, Dd - 1);
        const int i1y = min(i0y + 1, Hh - 1);
        const int i1z = min(i0z + 1, Ww - 1);

        const float d1x = (float)i1x - lxf, d0x = 1.0f - d1x;
        const float d1y = (float)i1y - lyf, d0y = 1.0f - d1y;
        const float d1z = (float)i1z - lzf, d0z = 1.0f - d1z;

        // region-local coords, UNCLAMPED (ok lanes are in-bounds by proof)
        const int a0x = i0x - ox, a1x = i1x - ox;
        const int a0y = i0y - oy, a1y = i1y - oy;
        const int a0z = i0z - oz, a1z = i1z - oz;

        const int r00 = (a0x * RH + a0y) * RWP;
        const int r01 = (a0x * RH + a1y) * RWP;
        const int r10 = (a1x * RH + a0y) * RWP;
        const int r11 = (a1x * RH + a1y) * RWP;
        const v2f c000 = svv[r00 + a0z], c001 = svv[r00 + a1z];
        const v2f c010 = svv[r01 + a0z], c011 = svv[r01 + a1z];
        const v2f c100 = svv[r10 + a0z], c101 = svv[r10 + a1z];
        const v2f c110 = svv[r11 + a0z], c111 = svv[r11 + a1z];

        // packed weights: zp = (d1z, d0z); wpXY = xyXY * zp  (v_pk_mul_f32)
        const v2f zp = (v2f){d1z, d0z};
        const float xy00 = d1x * d1y, xy01 = d1x * d0y;
        const float xy10 = d0x * d1y, xy11 = d0x * d0y;
        const v2f wp00 = xy00 * zp;   // (w000, w001)
        const v2f wp01 = xy01 * zp;   // (w010, w011)
        const v2f wp10 = xy10 * zp;   // (w100, w101)
        const v2f wp11 = xy11 * zp;   // (w110, w111)

        // packed accumulate over channels (v_pk_fma_f32); per-element ops
        // and order identical to the scalar reference chain.
        o = splat2(wp00.x) * c000;
        o = __builtin_elementwise_fma(splat2(wp00.y), c001, o);
        o = __builtin_elementwise_fma(splat2(wp01.x), c010, o);
        o = __builtin_elementwise_fma(splat2(wp01.y), c011, o);
        o = __builtin_elementwise_fma(splat2(wp10.x), c100, o);
        o = __builtin_elementwise_fma(splat2(wp10.y), c101, o);
        o = __builtin_elementwise_fma(splat2(wp11.x), c110, o);
        o = __builtin_elementwise_fma(splat2(wp11.y), c111, o);
    };

    // ---- both samples: one straight-line block, no divergent CFG ----
    v2f o1, o2;
    bool ok1, ok2;
    sample_lds(d, w,     fA.x, fA.y, fA.z, o1, ok1);
    sample_lds(d, w + 1, fA.w, fB.x, fB.y, o2, ok2);

    // ---- deferred rare fixup (wave-uniform skip for ~all waves) ----
    if (!__all(ok1 && ok2)) {
        if (!ok1) {
            float a, bch;
            sample_global(v2, d, h, w, fA.x, fA.y, fA.z, a, bch);
            o1 = (v2f){a, bch};
        }
        if (!ok2) {
            float a, bch;
            sample_global(v2, d, h, w + 1, fA.w, fB.x, fB.y, a, bch);
            o2 = (v2f){a, bch};
        }
    }

    // both voxels' outputs are adjacent float2s -> one 16B-aligned store
    *reinterpret_cast<float4*>(reinterpret_cast<float2*>(out) + gidx) =
        make_float4(o1.x, o1.y, o2.x, o2.y);
}

extern "C" void kernel_launch(void* const* d_in, const int* in_sizes, int n_in,
                              void* d_out, int out_size, void* d_ws, size_t ws_size,
                              hipStream_t stream)
{
    const float* vol  = (const float*)d_in[0];   // [2,160,192,160,2] f32
    const float* flow = (const float*)d_in[1];   // [2,160,192,160,3] f32
    float* out = (float*)d_out;                  // [2,160,192,160,2] f32

    SpatialTransformer_44418551776013_kernel<<<NBLK, BLOCK, LDS_BYTES, stream>>>(vol, flow, out);
}

// Round 14
// 65.271 us; speedup vs baseline: 1.0623x; 1.0623x over previous
//
#include <hip/hip_runtime.h>

// Trilinear warp (SpatialTransformer): vol [B=2,D=160,H=192,W=160,C=2] f32,
// flow [B,D,H,W,3] f32 ('ij'). Output f32, same shape as vol.
//
// R13 lesson: instruction cuts reduced VALU time (42->36us) but dur got
// WORSE (65.8->69.3) => latency-bound, and the packed v_pk_fma chain cut
// ILP (4 indep FMA chains/thread -> 2), lengthening stalls. R14 = R13 with
// scalar dual-chain FMA restored (single-variable A/B): keeps no-clamp LDS
// coords, flow-based ok-test, interior staging fast path, DMA staging.

constexpr int Bb = 2, Dd = 160, Hh = 192, Ww = 160;
constexpr int HW  = Hh * Ww;          // 30720
constexpr int VOX = Dd * HW;          // 4,915,200 voxels per batch

constexpr int TD = 8,  TH = 16, TW = 16;   // output tile (2048 voxels)
constexpr int RD = TD + 8;                 // 16  staged region (halo 4)
constexpr int RH = TH + 8;                 // 24
constexpr int RW = TW + 8;                 // 24  (extent always even)
constexpr int RWP = 24;                    // UNPADDED row stride (float2) — linear for DMA
constexpr int QROW = RW / 2;               // 12 float4 quads per row
constexpr int NQ = RD * RH * QROW;         // 4608 staged quads (i*16B linear)
constexpr int ND = Dd / TD, NH = Hh / TH, NW = Ww / TW;   // 20, 12, 10
constexpr int NBLK = Bb * ND * NH * NW;                   // 4800
constexpr int BLOCK = 1024;                // 16 waves; 2 voxels per thread
constexpr size_t LDS_BYTES = (size_t)NQ * 16;             // 73728 B

// Exact reference math + global gathers — rare out-of-region lanes only.
// Identical formulas/op-order to the reference.
__device__ __forceinline__ void sample_global(const float2* __restrict__ v2,
                                              int d, int h, int w,
                                              float fx, float fy, float fz,
                                              float& oxv, float& oyv)
{
    const float mx = (float)(Dd - 1), my = (float)(Hh - 1), mz = (float)(Ww - 1);
    const float lxf = (float)d + fx;
    const float lyf = (float)h + fy;
    const float lzf = (float)w + fz;

    const float l0x = fminf(fmaxf(floorf(lxf), 0.0f), mx);
    const float l0y = fminf(fmaxf(floorf(lyf), 0.0f), my);
    const float l0z = fminf(fmaxf(floorf(lzf), 0.0f), mz);
    const float l1x = fminf(l0x + 1.0f, mx);
    const float l1y = fminf(l0y + 1.0f, my);
    const float l1z = fminf(l0z + 1.0f, mz);

    const float d1x = l1x - lxf, d0x = 1.0f - d1x;
    const float d1y = l1y - lyf, d0y = 1.0f - d1y;
    const float d1z = l1z - lzf, d0z = 1.0f - d1z;

    const int i0x = (int)l0x, i1x = (int)l1x;
    const int i0y = (int)l0y, i1y = (int)l1y;
    const int i0z = (int)l0z, i1z = (int)l1z;

    const int rx0 = i0x * HW, rx1 = i1x * HW;
    const int ry0 = i0y * Ww, ry1 = i1y * Ww;
    const float2 c000 = v2[rx0 + ry0 + i0z], c001 = v2[rx0 + ry0 + i1z];
    const float2 c010 = v2[rx0 + ry1 + i0z], c011 = v2[rx0 + ry1 + i1z];
    const float2 c100 = v2[rx1 + ry0 + i0z], c101 = v2[rx1 + ry0 + i1z];
    const float2 c110 = v2[rx1 + ry1 + i0z], c111 = v2[rx1 + ry1 + i1z];

    const float w000 = d1x * d1y * d1z, w001 = d1x * d1y * d0z;
    const float w010 = d1x * d0y * d1z, w011 = d1x * d0y * d0z;
    const float w100 = d0x * d1y * d1z, w101 = d0x * d1y * d0z;
    const float w110 = d0x * d0y * d1z, w111 = d0x * d0y * d0z;

    oxv = w000 * c000.x;
    oyv = w000 * c000.y;
    oxv = fmaf(w001, c001.x, oxv);  oyv = fmaf(w001, c001.y, oyv);
    oxv = fmaf(w010, c010.x, oxv);  oyv = fmaf(w010, c010.y, oyv);
    oxv = fmaf(w011, c011.x, oxv);  oyv = fmaf(w011, c011.y, oyv);
    oxv = fmaf(w100, c100.x, oxv);  oyv = fmaf(w100, c100.y, oyv);
    oxv = fmaf(w101, c101.x, oxv);  oyv = fmaf(w101, c101.y, oyv);
    oxv = fmaf(w110, c110.x, oxv);  oyv = fmaf(w110, c110.y, oyv);
    oxv = fmaf(w111, c111.x, oxv);  oyv = fmaf(w111, c111.y, oyv);
}

__global__ __launch_bounds__(BLOCK, 8)   // 8 waves/EU => VGPR<=64 => 2 blocks/CU
void SpatialTransformer_44418551776013_kernel(const float* __restrict__ vol,
                                              const float* __restrict__ flow,
                                              float* __restrict__ out)
{
    extern __shared__ float2 sv[];   // [RD][RH][RWP], linear
    const int tid = threadIdx.x;

    // bijective XCD swizzle (NBLK % 8 == 0). Validated: FETCH 222 -> 132 MB.
    constexpr int CPX = NBLK / 8;    // 600
    int bid = (int)(blockIdx.x % 8) * CPX + (int)(blockIdx.x / 8);

    const int bw = bid % NW;  bid /= NW;
    const int bh = bid % NH;  bid /= NH;
    const int bd = bid % ND;
    const int b  = bid / ND;
    const int d0 = bd * TD, h0 = bh * TH, w0 = bw * TW;

    // staged region = clip(tile +- 4); block-uniform -> SGPRs
    const int ox = max(0, d0 - 4), oy = max(0, h0 - 4), oz = max(0, w0 - 4);
    const int ex = min(Dd - 1, d0 + TD + 3) - ox + 1;   // <= RD
    const int ey = min(Hh - 1, h0 + TH + 3) - oy + 1;   // <= RH
    const int ez = min(Ww - 1, w0 + TW + 3) - oz + 1;   // <= RW, even
    const int qz = ez >> 1;

    // compute mapping: (td, th, tw2); thread owns voxels (d,h,w) & (d,h,w+1)
    const int tw2 = tid & 7;             // w-pair index 0..7
    const int th  = (tid >> 3) & 15;     // 0..15
    const int td  = tid >> 7;            // 0..7
    const int h = h0 + th;
    const int w = w0 + 2 * tw2;
    const int d = d0 + td;
    const int gidx = ((b * Dd + d) * Hh + h) * Ww + w;   // even

    // flow for BOTH voxels = 6 contiguous floats: float4 + float2
    const float4 fA = *reinterpret_cast<const float4*>(flow + (size_t)gidx * 3);
    const float2 fB = *reinterpret_cast<const float2*>(flow + (size_t)gidx * 3 + 4);
    // voxel 1: (fA.x, fA.y, fA.z)   voxel 2: (fA.w, fB.x, fB.y)

    const float2* __restrict__ v2 =
        reinterpret_cast<const float2*>(vol) + (size_t)b * VOX;

    // ---- stage region via global_load_lds DMA (16B/lane, linear dest) ----
    // Interior blocks (60%): clamp-free body (uniform SGPR branch).
    if ((ex == RD) & (ey == RH) & (ez == RW)) {
        #pragma unroll 1
        for (int k = 0; k < 5; ++k) {
            const int i = tid + k * BLOCK;
            if (i < NQ) {                        // wave-uniform tail (512-aligned)
                const int lq = i % QROW;         // compile-time divisors
                const int t  = i / QROW;
                const int ly = t % RH;
                const int lx = t / RH;
                const float2* src =
                    v2 + ((size_t)(ox + lx) * HW + (oy + ly) * Ww + oz + 2 * lq);
                __builtin_amdgcn_global_load_lds(
                    (const __attribute__((address_space(1))) void*)src,
                    (__attribute__((address_space(3))) void*)(sv + (size_t)2 * i),
                    16, 0, 0);
            }
        }
    } else {
        #pragma unroll 1
        for (int k = 0; k < 5; ++k) {
            const int i = tid + k * BLOCK;
            if (i < NQ) {
                int lq = i % QROW;
                const int t  = i / QROW;
                int ly = t % RH;
                int lx = t / RH;
                lx = min(lx, ex - 1);  ly = min(ly, ey - 1);  lq = min(lq, qz - 1);
                const float2* src =
                    v2 + ((size_t)(ox + lx) * HW + (oy + ly) * Ww + oz + 2 * lq);
                __builtin_amdgcn_global_load_lds(
                    (const __attribute__((address_space(1))) void*)src,
                    (__attribute__((address_space(3))) void*)(sv + (size_t)2 * i),
                    16, 0, 0);
            }
        }
    }
    __syncthreads();   // drains vmcnt(0) before s_barrier

    // Branchless LDS sample. ok = flow in [-4,4)^3 => all clamped corner
    // indices provably inside the staged clipped region (incl. volume
    // edges). not-ok lanes may read OOB LDS (HW returns 0, never faults) —
    // fixup overwrites them. Scalar dual-chain FMA (R14: packed reverted).
    auto sample_lds = [&](int dd, int ww, float fx, float fy, float fz,
                          float& oxv, float& oyv, bool& ok) {
        const float mn3 = fminf(fminf(fx, fy), fz);   // v_min3_f32
        const float mx3 = fmaxf(fmaxf(fx, fy), fz);   // v_max3_f32
        ok = (mn3 >= -4.0f) & (mx3 < 4.0f);

        const float lxf = (float)dd + fx;
        const float lyf = (float)h  + fy;
        const float lzf = (float)ww + fz;

        // integer floor path (R10-validated bit-identical)
        const int i0x = min(max(__float2int_rd(lxf), 0), Dd - 1);  // v_med3
        const int i0y = min(max(__float2int_rd(lyf), 0), Hh - 1);
        const int i0z = min(max(__float2int_rd(lzf), 0), Ww - 1);
        const int i1x = min(i0x + 1, Dd - 1);
        const int i1y = min(i0y + 1, Hh - 1);
        const int i1z = min(i0z + 1, Ww - 1);

        const float d1x = (float)i1x - lxf, d0x = 1.0f - d1x;
        const float d1y = (float)i1y - lyf, d0y = 1.0f - d1y;
        const float d1z = (float)i1z - lzf, d0z = 1.0f - d1z;

        // region-local coords, UNCLAMPED (ok lanes in-bounds by proof)
        const int a0x = i0x - ox, a1x = i1x - ox;
        const int a0y = i0y - oy, a1y = i1y - oy;
        const int a0z = i0z - oz, a1z = i1z - oz;

        const int r00 = (a0x * RH + a0y) * RWP;
        const int r01 = (a0x * RH + a1y) * RWP;
        const int r10 = (a1x * RH + a0y) * RWP;
        const int r11 = (a1x * RH + a1y) * RWP;
        const float2 c000 = sv[r00 + a0z], c001 = sv[r00 + a1z];
        const float2 c010 = sv[r01 + a0z], c011 = sv[r01 + a1z];
        const float2 c100 = sv[r10 + a0z], c101 = sv[r10 + a1z];
        const float2 c110 = sv[r11 + a0z], c111 = sv[r11 + a1z];

        const float xy00 = d1x * d1y, xy01 = d1x * d0y;
        const float xy10 = d0x * d1y, xy11 = d0x * d0y;
        const float w000 = xy00 * d1z, w001 = xy00 * d0z;
        const float w010 = xy01 * d1z, w011 = xy01 * d0z;
        const float w100 = xy10 * d1z, w101 = xy10 * d0z;
        const float w110 = xy11 * d1z, w111 = xy11 * d0z;

        oxv = w000 * c000.x;
        oyv = w000 * c000.y;
        oxv = fmaf(w001, c001.x, oxv);  oyv = fmaf(w001, c001.y, oyv);
        oxv = fmaf(w010, c010.x, oxv);  oyv = fmaf(w010, c010.y, oyv);
        oxv = fmaf(w011, c011.x, oxv);  oyv = fmaf(w011, c011.y, oyv);
        oxv = fmaf(w100, c100.x, oxv);  oyv = fmaf(w100, c100.y, oyv);
        oxv = fmaf(w101, c101.x, oxv);  oyv = fmaf(w101, c101.y, oyv);
        oxv = fmaf(w110, c110.x, oxv);  oyv = fmaf(w110, c110.y, oyv);
        oxv = fmaf(w111, c111.x, oxv);  oyv = fmaf(w111, c111.y, oyv);
    };

    // ---- both samples: one straight-line block, no divergent CFG ----
    float o1x, o1y, o2x, o2y;
    bool ok1, ok2;
    sample_lds(d, w,     fA.x, fA.y, fA.z, o1x, o1y, ok1);
    sample_lds(d, w + 1, fA.w, fB.x, fB.y, o2x, o2y, ok2);

    // ---- deferred rare fixup (wave-uniform skip for ~all waves) ----
    if (!__all(ok1 && ok2)) {
        if (!ok1) sample_global(v2, d, h, w,     fA.x, fA.y, fA.z, o1x, o1y);
        if (!ok2) sample_global(v2, d, h, w + 1, fA.w, fB.x, fB.y, o2x, o2y);
    }

    // both voxels' outputs are adjacent float2s -> one 16B-aligned store
    *reinterpret_cast<float4*>(reinterpret_cast<float2*>(out) + gidx) =
        make_float4(o1x, o1y, o2x, o2y);
}

extern "C" void kernel_launch(void* const* d_in, const int* in_sizes, int n_in,
                              void* d_out, int out_size, void* d_ws, size_t ws_size,
                              hipStream_t stream)
{
    const float* vol  = (const float*)d_in[0];   // [2,160,192,160,2] f32
    const float* flow = (const float*)d_in[1];   // [2,160,192,160,3] f32
    float* out = (float*)d_out;                  // [2,160,192,160,2] f32

    SpatialTransformer_44418551776013_kernel<<<NBLK, BLOCK, LDS_BYTES, stream>>>(vol, flow, out);
}